// Round 9
// baseline (104.576 us; speedup 1.0000x reference)
//
#include <hip/hip_runtime.h>
#include <stdint.h>

typedef unsigned long long u64;

#define D_DIM   10000
#define C_CLS   128
#define WPRP    192     // padded u64 words per (row-or-class, p)
#define NWORDS  160     // words actually produced by ballots (156 full + 4 tail)
#define NIT     40      // 256-element chunks per 10000-d vector
#define GRP     8       // classes per reduction group

__device__ __forceinline__ float wred64(float v) {
#pragma unroll
    for (int m = 1; m <= 32; m <<= 1) v += __shfl_xor(v, m);
    return v;
}
__device__ __forceinline__ int wred64i(int v) {
#pragma unroll
    for (int m = 1; m <= 32; m <<= 1) v += __shfl_xor(v, m);
    return v;
}

// Packed AM layout: each (class, word-lane) owns 18 contiguous u64 (144 B):
// p0 words 0-5, p1 6-11, p2 12-17.
__device__ __forceinline__ size_t am_idx(int c, int wi, int p) {
    return ((size_t)c * 32 + (unsigned)wi / 6u) * 18 + (size_t)p * 6 + (unsigned)wi % 6u;
}

// ---------------- Kernel A: PQ-HDC transform, one block per class ----------------
__global__ __launch_bounds__(256) void kA_transform(const float* __restrict__ am,
                                                    u64* __restrict__ amw,
                                                    float4* __restrict__ wtab)
{
    const int c = blockIdx.x;
    const int t = threadIdx.x;
    const int w = t >> 6;
    const int l = t & 63;

    __shared__ float redf[4];
    __shared__ int   sI[4][6];
    __shared__ float sF[4][3];

    const float* hvp = am + (size_t)c * D_DIM;

    float4 loss[10], hv[10];
#pragma unroll
    for (int k = 0; k < 10; ++k) {
        const int it = w + 4 * k;
        const int d0 = it * 256 + 4 * l;
        float4 x = make_float4(0.f, 0.f, 0.f, 0.f);
        if (d0 + 3 < D_DIM) x = *(const float4*)(hvp + d0);
        loss[k] = x; hv[k] = x;
    }

    int cnt[3]; float hX[3]; u64 sp[3];

#pragma unroll
    for (int p = 0; p < 3; ++p) {
        float sabs = 0.f;
#pragma unroll
        for (int k = 0; k < 10; ++k)
            sabs += fabsf(loss[k].x) + fabsf(loss[k].y) + fabsf(loss[k].z) + fabsf(loss[k].w);
        sabs = wred64(sabs);
        if (l == 0) redf[w] = sabs;
        __syncthreads();
        const float dot = redf[0] + redf[1] + redf[2] + redf[3];
        __syncthreads();
        const float dd = dot / (float)D_DIM;

        u64 bits = 0; int cc = 0; float hx = 0.f;
#pragma unroll
        for (int k = 0; k < 10; ++k) {
            const int it = w + 4 * k;
            const bool p0 = loss[k].x > 0.f;
            const bool p1 = loss[k].y > 0.f;
            const bool p2 = loss[k].z > 0.f;
            const bool p3 = loss[k].w > 0.f;
            const u64 b0 = __ballot(p0);
            const u64 b1 = __ballot(p1);
            const u64 b2 = __ballot(p2);
            const u64 b3 = __ballot(p3);
            if (l < 4) {
                const u64 bb = (l == 0) ? b0 : ((l == 1) ? b1 : ((l == 2) ? b2 : b3));
                amw[am_idx(c, it * 4 + l, p)] = bb;
            }
            bits |= ((u64)p0 << (4 * k)) | ((u64)p1 << (4 * k + 1))
                  | ((u64)p2 << (4 * k + 2)) | ((u64)p3 << (4 * k + 3));
            cc += (int)p0 + (int)p1 + (int)p2 + (int)p3;
            hx += (p0 ? hv[k].x : -hv[k].x) + (p1 ? hv[k].y : -hv[k].y)
                + (p2 ? hv[k].z : -hv[k].z) + (p3 ? hv[k].w : -hv[k].w);
            float4 L = loss[k];
            L.x -= p0 ? dd : -dd; L.y -= p1 ? dd : -dd;
            L.z -= p2 ? dd : -dd; L.w -= p3 ? dd : -dd;
            const int d0 = it * 256 + 4 * l;
            if (!(d0 + 3 < D_DIM)) L = make_float4(0.f, 0.f, 0.f, 0.f);
            loss[k] = L;
        }
        if (t < WPRP - NWORDS) amw[am_idx(c, NWORDS + t, p)] = 0ull;
        sp[p] = bits; cnt[p] = cc; hX[p] = hx;
    }

    int vi[6] = { cnt[0], cnt[1], cnt[2],
                  static_cast<int>(__popcll(sp[0] ^ sp[1])),
                  static_cast<int>(__popcll(sp[0] ^ sp[2])),
                  static_cast<int>(__popcll(sp[1] ^ sp[2])) };
#pragma unroll
    for (int i = 0; i < 6; ++i) vi[i] = wred64i(vi[i]);
    float vf[3] = { hX[0], hX[1], hX[2] };
#pragma unroll
    for (int i = 0; i < 3; ++i) vf[i] = wred64(vf[i]);
    if (l == 0) {
#pragma unroll
        for (int i = 0; i < 6; ++i) sI[w][i] = vi[i];
#pragma unroll
        for (int i = 0; i < 3; ++i) sF[w][i] = vf[i];
    }
    __syncthreads();
    if (t == 0) {
        int a0 = 0, a1 = 0, a2 = 0, X01 = 0, X02 = 0, X12 = 0;
        float h0f = 0, h1f = 0, h2f = 0;
        for (int i = 0; i < 4; ++i) {
            a0 += sI[i][0]; a1 += sI[i][1]; a2 += sI[i][2];
            X01 += sI[i][3]; X02 += sI[i][4]; X12 += sI[i][5];
            h0f += sF[i][0]; h1f += sF[i][1]; h2f += sF[i][2];
        }
        const double Dv = (double)D_DIM;
        const double h0 = h0f, h1 = h1f, h2 = h2f;
        const double g01 = Dv - 2.0 * X01, g02 = Dv - 2.0 * X02, g12 = Dv - 2.0 * X12;
        const double A00 = Dv * Dv - g12 * g12;
        const double A01 = g02 * g12 - g01 * Dv;
        const double A02 = g01 * g12 - g02 * Dv;
        const double A11 = Dv * Dv - g02 * g02;
        const double A12 = g02 * g01 - Dv * g12;
        const double A22 = Dv * Dv - g01 * g01;
        const double det = Dv * A00 + g01 * A01 + g02 * A02;
        const double w0 = (A00 * h0 + A01 * h1 + A02 * h2) / det;
        const double w1 = (A01 * h0 + A11 * h1 + A12 * h2) / det;
        const double w2 = (A02 * h0 + A12 * h1 + A22 * h2) / det;
        const double s = w0 * w0 + w1 * w1 + w2 * w2;
        const double f0 = w0 * w0 / s, f1 = w1 * w1 / s, f2 = w2 * w2 / s;
        const double cb = -(f0 * a0 + f1 * a1 + f2 * a2);
        wtab[c] = make_float4((float)f0, (float)f1, (float)f2, (float)cb);
    }
}

// ---------------- Kernel B helpers (all indices compile-time constant) ----------------
struct AmBatch { ulonglong2 v[9]; };

__device__ __forceinline__ void amload(AmBatch& b, const u64* __restrict__ amw,
                                       int c, int wl) {
    const u64* ap = amw + ((size_t)c * 32 + wl) * 18;
#pragma unroll
    for (int i = 0; i < 9; ++i) b.v[i] = *(const ulonglong2*)(ap + 2 * i);
}

// ---------------- Kernel B: fused query pack + pseudo-Hamming similarity ----------------
// 4 rows/block, grid = B/4. Wave w packs row w, handles classes [32w,32w+32) for all
// 4 rows (lane halves rh own row pairs; both halves read identical AM addresses).
// 2-deep register double-buffer (P/N batches) prefetches class c+1 while computing c;
// first batch issued before the pack loop so L2 latency hides under the query stream.
// Group reduce via per-wave padded-LDS transpose, NO __syncthreads (intra-wave only)
// so prefetches stay in flight across groups.
__global__ __launch_bounds__(256, 4) void kB_phs(const float* __restrict__ query,
                                                 const u64* __restrict__ amw,
                                                 const float4* __restrict__ wtab,
                                                 float* __restrict__ out)
{
    __shared__ u64 qlds[4 * WPRP];          // 6144 B
    __shared__ float4 wsh[C_CLS];           // 2048 B
    __shared__ float part[4][4][GRP][33];   // [wave][row_loc][cc][wl] 16896 B
    const int t = threadIdx.x;
    const int w = t >> 6;
    const int l = t & 63;
    const int r0 = blockIdx.x * 4;
    const int wl = l & 31;
    const int c0 = 32 * w;

    if (t < C_CLS) wsh[t] = wtab[t];

    // initial AM prefetch: latency hides under the pack phase
    AmBatch P, N;
    amload(P, amw, c0, wl);

    // ---- pack: wave w packs row r0 + w ----
    {
        const float* qp = query + (size_t)(r0 + w) * D_DIM;
        u64* qrow = qlds + w * WPRP;
        for (int it = 0; it < NIT; ++it) {
            const int d0 = it * 256 + 4 * l;
            float4 x = make_float4(0.f, 0.f, 0.f, 0.f);
            if (d0 + 3 < D_DIM) x = *(const float4*)(qp + d0);
            const u64 b0 = __ballot(x.x > 0.f);
            const u64 b1 = __ballot(x.y > 0.f);
            const u64 b2 = __ballot(x.z > 0.f);
            const u64 b3 = __ballot(x.w > 0.f);
            if (l < 4) qrow[it * 4 + l] = (l == 0) ? b0 : ((l == 1) ? b1 : ((l == 2) ? b2 : b3));
        }
        if (l < 32) qrow[NWORDS + l] = 0ull;
    }
    __syncthreads();

    // ---- per-lane q words: rows 2rh, 2rh+1, word slot wl (6 u64 each) ----
    const int rh = l >> 5;
    const int rA = 2 * rh, rB = 2 * rh + 1;

    const u64* qaP = qlds + rA * WPRP + wl * 6;
    const u64* qbP = qlds + rB * WPRP + wl * 6;
    u64 qa[6], qb[6];
#pragma unroll
    for (int i = 0; i < 6; ++i) { qa[i] = qaP[i]; qb[i] = qbP[i]; }

    int qsA = 0, qsB = 0;
#pragma unroll
    for (int i = 0; i < 6; ++i) { qsA += (int)__popcll(qa[i]); qsB += (int)__popcll(qb[i]); }
    const float offA = 312.5f - (float)qsA;   // D/32 - qs_lane (exact in f32)
    const float offB = 312.5f - (float)qsB;

    // reader mapping for the transpose-reduce
    const int o = l >> 1;            // 0..31
    const int row_loc = o >> 3;      // 0..3
    const int cc = o & 7;            // 0..7
    const int h = l & 1;

    float (*pw)[GRP][33] = part[w];

    for (int g = 0; g < 4; ++g) {
        const int cbase = c0 + g * GRP;
        float accA[GRP], accB[GRP];
#pragma unroll
        for (int ii = 0; ii < 4; ++ii) {
            const int c = cbase + 2 * ii;
            amload(N, amw, c + 1, wl);        // prefetch odd class
            {                                  // compute even class from P
                int pA[3] = {0, 0, 0}, pB[3] = {0, 0, 0};
#pragma unroll
                for (int p = 0; p < 3; ++p)
#pragma unroll
                    for (int j = 0; j < 3; ++j) {
                        const ulonglong2 vv = P.v[p * 3 + j];
                        pA[p] += (int)(__popcll(qa[2 * j] & vv.x) + __popcll(qa[2 * j + 1] & vv.y));
                        pB[p] += (int)(__popcll(qb[2 * j] & vv.x) + __popcll(qb[2 * j + 1] & vv.y));
                    }
                const float4 wv = wsh[c];
                const float cw = wv.w * 0.03125f;
                accA[2 * ii] = fmaf(2.f, wv.x * (float)pA[0] + wv.y * (float)pA[1] + wv.z * (float)pA[2], offA + cw);
                accB[2 * ii] = fmaf(2.f, wv.x * (float)pB[0] + wv.y * (float)pB[1] + wv.z * (float)pB[2], offB + cw);
            }
            int c2 = c + 2;                    // prefetch next even (wraps at group end)
            if (c2 > c0 + 31) c2 = c0;
            amload(P, amw, c2, wl);
            {                                  // compute odd class from N
                int pA[3] = {0, 0, 0}, pB[3] = {0, 0, 0};
#pragma unroll
                for (int p = 0; p < 3; ++p)
#pragma unroll
                    for (int j = 0; j < 3; ++j) {
                        const ulonglong2 vv = N.v[p * 3 + j];
                        pA[p] += (int)(__popcll(qa[2 * j] & vv.x) + __popcll(qa[2 * j + 1] & vv.y));
                        pB[p] += (int)(__popcll(qb[2 * j] & vv.x) + __popcll(qb[2 * j + 1] & vv.y));
                    }
                const float4 wv = wsh[c + 1];
                const float cw = wv.w * 0.03125f;
                accA[2 * ii + 1] = fmaf(2.f, wv.x * (float)pA[0] + wv.y * (float)pA[1] + wv.z * (float)pA[2], offA + cw);
                accB[2 * ii + 1] = fmaf(2.f, wv.x * (float)pB[0] + wv.y * (float)pB[1] + wv.z * (float)pB[2], offB + cw);
            }
        }

        // ---- per-wave transpose-reduce through LDS (no barriers needed) ----
#pragma unroll
        for (int i = 0; i < GRP; ++i) {
            pw[rA][i][wl] = accA[i];
            pw[rB][i][wl] = accB[i];
        }
        float s = 0.f;
#pragma unroll
        for (int j = 0; j < 16; ++j) s += pw[row_loc][cc][h * 16 + j];
        s += __shfl_xor(s, 1);
        if (h == 0)
            out[(size_t)(r0 + row_loc) * C_CLS + (cbase + cc)] = s;
    }
}

extern "C" void kernel_launch(void* const* d_in, const int* in_sizes, int n_in,
                              void* d_out, int out_size, void* d_ws, size_t ws_size,
                              hipStream_t stream)
{
    const float* query = (const float*)d_in[0];
    const float* am    = (const float*)d_in[1];
    float* out = (float*)d_out;

    float4* wtab = (float4*)d_ws;                       // 128 * 16 B
    u64* amw = (u64*)((char*)d_ws + 2048);              // 128*32*18 u64 = 576 KiB

    const int B = in_sizes[0] / D_DIM;                  // 4096

    hipLaunchKernelGGL(kA_transform, dim3(C_CLS), dim3(256), 0, stream, am, amw, wtab);
    hipLaunchKernelGGL(kB_phs, dim3(B / 4), dim3(256), 0, stream, query, amw, wtab, out);
}

// Round 11
// 97.245 us; speedup vs baseline: 1.0754x; 1.0754x over previous
//
#include <hip/hip_runtime.h>
#include <stdint.h>

typedef unsigned long long u64;
typedef __attribute__((ext_vector_type(4))) unsigned int u32x4;

#define D_DIM   10000
#define C_CLS   128
#define WPRP    192     // padded u64 words per (row-or-class, p)
#define NWORDS  160     // words actually produced by ballots (156 full + 4 tail)
#define NIT     40      // 256-element chunks per 10000-d vector
#define GRP     8       // classes per reduction group

__device__ __forceinline__ float wred64(float v) {
#pragma unroll
    for (int m = 1; m <= 32; m <<= 1) v += __shfl_xor(v, m);
    return v;
}
__device__ __forceinline__ int wred64i(int v) {
#pragma unroll
    for (int m = 1; m <= 32; m <<= 1) v += __shfl_xor(v, m);
    return v;
}

// Packed AM layout: each (class, word-lane) owns 18 contiguous u64 (144 B):
// p0 words 0-5, p1 6-11, p2 12-17.
__device__ __forceinline__ size_t am_idx(int c, int wi, int p) {
    return ((size_t)c * 32 + (unsigned)wi / 6u) * 18 + (size_t)p * 6 + (unsigned)wi % 6u;
}

// ---------------- Kernel A: PQ-HDC transform, one block per class ----------------
__global__ __launch_bounds__(256) void kA_transform(const float* __restrict__ am,
                                                    u64* __restrict__ amw,
                                                    float4* __restrict__ wtab)
{
    const int c = blockIdx.x;
    const int t = threadIdx.x;
    const int w = t >> 6;
    const int l = t & 63;

    __shared__ float redf[4];
    __shared__ int   sI[4][6];
    __shared__ float sF[4][3];

    const float* hvp = am + (size_t)c * D_DIM;

    float4 loss[10], hv[10];
#pragma unroll
    for (int k = 0; k < 10; ++k) {
        const int it = w + 4 * k;
        const int d0 = it * 256 + 4 * l;
        float4 x = make_float4(0.f, 0.f, 0.f, 0.f);
        if (d0 + 3 < D_DIM) x = *(const float4*)(hvp + d0);
        loss[k] = x; hv[k] = x;
    }

    int cnt[3]; float hX[3]; u64 sp[3];

#pragma unroll
    for (int p = 0; p < 3; ++p) {
        float sabs = 0.f;
#pragma unroll
        for (int k = 0; k < 10; ++k)
            sabs += fabsf(loss[k].x) + fabsf(loss[k].y) + fabsf(loss[k].z) + fabsf(loss[k].w);
        sabs = wred64(sabs);
        if (l == 0) redf[w] = sabs;
        __syncthreads();
        const float dot = redf[0] + redf[1] + redf[2] + redf[3];
        __syncthreads();
        const float dd = dot / (float)D_DIM;

        u64 bits = 0; int cc = 0; float hx = 0.f;
#pragma unroll
        for (int k = 0; k < 10; ++k) {
            const int it = w + 4 * k;
            const bool p0 = loss[k].x > 0.f;
            const bool p1 = loss[k].y > 0.f;
            const bool p2 = loss[k].z > 0.f;
            const bool p3 = loss[k].w > 0.f;
            const u64 b0 = __ballot(p0);
            const u64 b1 = __ballot(p1);
            const u64 b2 = __ballot(p2);
            const u64 b3 = __ballot(p3);
            if (l < 4) {
                const u64 bb = (l == 0) ? b0 : ((l == 1) ? b1 : ((l == 2) ? b2 : b3));
                amw[am_idx(c, it * 4 + l, p)] = bb;
            }
            bits |= ((u64)p0 << (4 * k)) | ((u64)p1 << (4 * k + 1))
                  | ((u64)p2 << (4 * k + 2)) | ((u64)p3 << (4 * k + 3));
            cc += (int)p0 + (int)p1 + (int)p2 + (int)p3;
            hx += (p0 ? hv[k].x : -hv[k].x) + (p1 ? hv[k].y : -hv[k].y)
                + (p2 ? hv[k].z : -hv[k].z) + (p3 ? hv[k].w : -hv[k].w);
            float4 L = loss[k];
            L.x -= p0 ? dd : -dd; L.y -= p1 ? dd : -dd;
            L.z -= p2 ? dd : -dd; L.w -= p3 ? dd : -dd;
            const int d0 = it * 256 + 4 * l;
            if (!(d0 + 3 < D_DIM)) L = make_float4(0.f, 0.f, 0.f, 0.f);
            loss[k] = L;
        }
        if (t < WPRP - NWORDS) amw[am_idx(c, NWORDS + t, p)] = 0ull;
        sp[p] = bits; cnt[p] = cc; hX[p] = hx;
    }

    int vi[6] = { cnt[0], cnt[1], cnt[2],
                  static_cast<int>(__popcll(sp[0] ^ sp[1])),
                  static_cast<int>(__popcll(sp[0] ^ sp[2])),
                  static_cast<int>(__popcll(sp[1] ^ sp[2])) };
#pragma unroll
    for (int i = 0; i < 6; ++i) vi[i] = wred64i(vi[i]);
    float vf[3] = { hX[0], hX[1], hX[2] };
#pragma unroll
    for (int i = 0; i < 3; ++i) vf[i] = wred64(vf[i]);
    if (l == 0) {
#pragma unroll
        for (int i = 0; i < 6; ++i) sI[w][i] = vi[i];
#pragma unroll
        for (int i = 0; i < 3; ++i) sF[w][i] = vf[i];
    }
    __syncthreads();
    if (t == 0) {
        int a0 = 0, a1 = 0, a2 = 0, X01 = 0, X02 = 0, X12 = 0;
        float h0f = 0, h1f = 0, h2f = 0;
        for (int i = 0; i < 4; ++i) {
            a0 += sI[i][0]; a1 += sI[i][1]; a2 += sI[i][2];
            X01 += sI[i][3]; X02 += sI[i][4]; X12 += sI[i][5];
            h0f += sF[i][0]; h1f += sF[i][1]; h2f += sF[i][2];
        }
        const double Dv = (double)D_DIM;
        const double h0 = h0f, h1 = h1f, h2 = h2f;
        const double g01 = Dv - 2.0 * X01, g02 = Dv - 2.0 * X02, g12 = Dv - 2.0 * X12;
        const double A00 = Dv * Dv - g12 * g12;
        const double A01 = g02 * g12 - g01 * Dv;
        const double A02 = g01 * g12 - g02 * Dv;
        const double A11 = Dv * Dv - g02 * g02;
        const double A12 = g02 * g01 - Dv * g12;
        const double A22 = Dv * Dv - g01 * g01;
        const double det = Dv * A00 + g01 * A01 + g02 * A02;
        const double w0 = (A00 * h0 + A01 * h1 + A02 * h2) / det;
        const double w1 = (A01 * h0 + A11 * h1 + A12 * h2) / det;
        const double w2 = (A02 * h0 + A12 * h1 + A22 * h2) / det;
        const double s = w0 * w0 + w1 * w1 + w2 * w2;
        const double f0 = w0 * w0 / s, f1 = w1 * w1 / s, f2 = w2 * w2 / s;
        const double cb = -(f0 * a0 + f1 * a1 + f2 * a2);
        wtab[c] = make_float4((float)f0, (float)f1, (float)f2, (float)cb);
    }
}

// ---------------- Kernel B helpers ----------------
struct AmBatch { u32x4 r[9]; };

// Atomic 9-load batch: the asm block cannot be split, so all 9 dwordx4 issue
// back-to-back (one latency, not nine). vmcnt(0) drained inside because the
// compiler does not model asm-internal VMEM.
__device__ __forceinline__ void amload_asm(AmBatch& b, const u64* ap) {
    asm("global_load_dwordx4 %0, %9, off\n\t"
        "global_load_dwordx4 %1, %9, off offset:16\n\t"
        "global_load_dwordx4 %2, %9, off offset:32\n\t"
        "global_load_dwordx4 %3, %9, off offset:48\n\t"
        "global_load_dwordx4 %4, %9, off offset:64\n\t"
        "global_load_dwordx4 %5, %9, off offset:80\n\t"
        "global_load_dwordx4 %6, %9, off offset:96\n\t"
        "global_load_dwordx4 %7, %9, off offset:112\n\t"
        "global_load_dwordx4 %8, %9, off offset:128\n\t"
        "s_waitcnt vmcnt(0)"
        : "=v"(b.r[0]), "=v"(b.r[1]), "=v"(b.r[2]), "=v"(b.r[3]), "=v"(b.r[4]),
          "=v"(b.r[5]), "=v"(b.r[6]), "=v"(b.r[7]), "=v"(b.r[8])
        : "v"(ap));
}

// Batched 4-chunk query load (chunk stride = 256 floats = 1024 B, fits offset imm).
__device__ __forceinline__ void qload4_asm(float4& x0, float4& x1, float4& x2, float4& x3,
                                           const float* p) {
    asm("global_load_dwordx4 %0, %4, off\n\t"
        "global_load_dwordx4 %1, %4, off offset:1024\n\t"
        "global_load_dwordx4 %2, %4, off offset:2048\n\t"
        "global_load_dwordx4 %3, %4, off offset:3072\n\t"
        "s_waitcnt vmcnt(0)"
        : "=v"(x0), "=v"(x1), "=v"(x2), "=v"(x3)
        : "v"(p));
}

// ---------------- Kernel B: fused query pack + pseudo-Hamming similarity ----------------
// 4 rows/block, grid = B/4. Wave w packs row w, handles classes [32w,32w+32) for all
// 4 rows (lane halves rh own row pairs; both halves read identical AM addresses).
// AM loads batched via inline asm (one L2 latency per class). Group reduce via
// per-wave padded-LDS transpose, no barriers, coalesced stores.
__global__ __launch_bounds__(256, 4) void kB_phs(const float* __restrict__ query,
                                                 const u64* __restrict__ amw,
                                                 const float4* __restrict__ wtab,
                                                 float* __restrict__ out)
{
    __shared__ u64 qlds[4 * WPRP];          // 6144 B
    __shared__ float4 wsh[C_CLS];           // 2048 B
    __shared__ float part[4][4][GRP][33];   // [wave][row_loc][cc][wl] 16896 B
    const int t = threadIdx.x;
    const int w = t >> 6;
    const int l = t & 63;
    const int r0 = blockIdx.x * 4;
    const int wl = l & 31;
    const int c0 = 32 * w;

    if (t < C_CLS) wsh[t] = wtab[t];

    // ---- pack: wave w packs row r0 + w (batched loads for chunks 0..35) ----
    {
        const float* qp = query + (size_t)(r0 + w) * D_DIM;
        u64* qrow = qlds + w * WPRP;
        for (int ib = 0; ib < 9; ++ib) {
            const int it0 = ib * 4;
            float4 x0, x1, x2, x3;
            qload4_asm(x0, x1, x2, x3, qp + it0 * 256 + 4 * l);
            float4 xs[4] = { x0, x1, x2, x3 };
#pragma unroll
            for (int k = 0; k < 4; ++k) {
                const u64 b0 = __ballot(xs[k].x > 0.f);
                const u64 b1 = __ballot(xs[k].y > 0.f);
                const u64 b2 = __ballot(xs[k].z > 0.f);
                const u64 b3 = __ballot(xs[k].w > 0.f);
                if (l < 4) qrow[(it0 + k) * 4 + l] =
                    (l == 0) ? b0 : ((l == 1) ? b1 : ((l == 2) ? b2 : b3));
            }
        }
        for (int it = 36; it < NIT; ++it) {
            const int d0 = it * 256 + 4 * l;
            float4 x = make_float4(0.f, 0.f, 0.f, 0.f);
            if (d0 + 3 < D_DIM) x = *(const float4*)(qp + d0);
            const u64 b0 = __ballot(x.x > 0.f);
            const u64 b1 = __ballot(x.y > 0.f);
            const u64 b2 = __ballot(x.z > 0.f);
            const u64 b3 = __ballot(x.w > 0.f);
            if (l < 4) qrow[it * 4 + l] = (l == 0) ? b0 : ((l == 1) ? b1 : ((l == 2) ? b2 : b3));
        }
        if (l < 32) qrow[NWORDS + l] = 0ull;
    }
    __syncthreads();

    // ---- per-lane q words as u32: rows 2rh, 2rh+1, word slot wl ----
    const int rh = l >> 5;
    const int rA = 2 * rh, rB = 2 * rh + 1;

    const u64* qaP = qlds + rA * WPRP + wl * 6;
    const u64* qbP = qlds + rB * WPRP + wl * 6;
    unsigned qa32[12], qb32[12];
#pragma unroll
    for (int i = 0; i < 6; ++i) {
        const u64 a = qaP[i], b = qbP[i];
        qa32[2 * i] = (unsigned)a; qa32[2 * i + 1] = (unsigned)(a >> 32);
        qb32[2 * i] = (unsigned)b; qb32[2 * i + 1] = (unsigned)(b >> 32);
    }

    int qsA = 0, qsB = 0;
#pragma unroll
    for (int i = 0; i < 12; ++i) { qsA += __popc(qa32[i]); qsB += __popc(qb32[i]); }
    const float offA = 312.5f - (float)qsA;   // D/32 - qs_lane (exact in f32)
    const float offB = 312.5f - (float)qsB;

    // reader mapping for the transpose-reduce
    const int o = l >> 1;            // 0..31
    const int row_loc = o >> 3;      // 0..3
    const int cc = o & 7;            // 0..7
    const int h = l & 1;

    float (*pw)[GRP][33] = part[w];

    for (int g = 0; g < 4; ++g) {
        const int cbase = c0 + g * GRP;
        float accA[GRP], accB[GRP];
#pragma unroll
        for (int i = 0; i < GRP; ++i) {
            const int c = cbase + i;
            AmBatch b;
            amload_asm(b, amw + ((size_t)c * 32 + wl) * 18);
            int pA[3] = {0, 0, 0}, pB[3] = {0, 0, 0};
#pragma unroll
            for (int p = 0; p < 3; ++p)
#pragma unroll
                for (int k = 0; k < 3; ++k) {
                    const u32x4 v = b.r[3 * p + k];
                    pA[p] += __popc(qa32[4 * k + 0] & v[0]) + __popc(qa32[4 * k + 1] & v[1])
                           + __popc(qa32[4 * k + 2] & v[2]) + __popc(qa32[4 * k + 3] & v[3]);
                    pB[p] += __popc(qb32[4 * k + 0] & v[0]) + __popc(qb32[4 * k + 1] & v[1])
                           + __popc(qb32[4 * k + 2] & v[2]) + __popc(qb32[4 * k + 3] & v[3]);
                }
            const float4 wv = wsh[c];
            const float cw = wv.w * 0.03125f;   // w.w / 32, exact
            accA[i] = fmaf(2.f, wv.x * (float)pA[0] + wv.y * (float)pA[1] + wv.z * (float)pA[2],
                           offA + cw);
            accB[i] = fmaf(2.f, wv.x * (float)pB[0] + wv.y * (float)pB[1] + wv.z * (float)pB[2],
                           offB + cw);
        }

        // ---- per-wave transpose-reduce through LDS (no barriers needed) ----
#pragma unroll
        for (int i = 0; i < GRP; ++i) {
            pw[rA][i][wl] = accA[i];
            pw[rB][i][wl] = accB[i];
        }
        float s = 0.f;
#pragma unroll
        for (int j = 0; j < 16; ++j) s += pw[row_loc][cc][h * 16 + j];
        s += __shfl_xor(s, 1);
        if (h == 0)
            out[(size_t)(r0 + row_loc) * C_CLS + (cbase + cc)] = s;
    }
}

extern "C" void kernel_launch(void* const* d_in, const int* in_sizes, int n_in,
                              void* d_out, int out_size, void* d_ws, size_t ws_size,
                              hipStream_t stream)
{
    const float* query = (const float*)d_in[0];
    const float* am    = (const float*)d_in[1];
    float* out = (float*)d_out;

    float4* wtab = (float4*)d_ws;                       // 128 * 16 B
    u64* amw = (u64*)((char*)d_ws + 2048);              // 128*32*18 u64 = 576 KiB

    const int B = in_sizes[0] / D_DIM;                  // 4096

    hipLaunchKernelGGL(kA_transform, dim3(C_CLS), dim3(256), 0, stream, am, amw, wtab);
    hipLaunchKernelGGL(kB_phs, dim3(B / 4), dim3(256), 0, stream, query, amw, wtab, out);
}